// Round 3
// baseline (831.725 us; speedup 1.0000x reference)
//
#include <hip/hip_runtime.h>
#include <hip/hip_bf16.h>

typedef __attribute__((ext_vector_type(8))) short short8;
typedef __attribute__((ext_vector_type(4))) float f32x4;

typedef const __attribute__((address_space(1))) void gvoid;
typedef __attribute__((address_space(3))) void lvoid;

// X: (32, 256, 64, 64) f32 ; W,B: (256, 256, 2, 2) f32 ; out: (32, 256, 128, 128) f32
// GEMM view: M = 131072 pixels, N = 1024 (col = o*4 + kh*2 + kw), K = 256.

__device__ __forceinline__ short f2bf(float f) {
    union { __hip_bfloat16 h; short s; } u; u.h = __float2bfloat16(f); return u.s;
}

// One-shot prep: W (256,256,2,2) f32 -> Bg[col][k] bf16 (1024 x 256), and
// bsum[col] = sum_c biases[o][c][kl].  Grid 256 (per o), 256 thr (per c).
__global__ __launch_bounds__(256) void prep_wb(
    const float* __restrict__ W, const float* __restrict__ B,
    short* __restrict__ Bg, float* __restrict__ bsum)
{
    const int o = blockIdx.x, c = threadIdx.x;
    const int wave = c >> 6, lane = c & 63;
    f32x4 w = *(const f32x4*)(W + ((size_t)o << 10) + (c << 2));
    #pragma unroll
    for (int kl = 0; kl < 4; ++kl)
        Bg[(size_t)(((o << 2) + kl) << 8) + c] = f2bf(w[kl]);

    f32x4 b = *(const f32x4*)(B + ((size_t)o << 10) + (c << 2));
    #pragma unroll
    for (int off = 32; off >= 1; off >>= 1) {
        b[0] += __shfl_down(b[0], off, 64);
        b[1] += __shfl_down(b[1], off, 64);
        b[2] += __shfl_down(b[2], off, 64);
        b[3] += __shfl_down(b[3], off, 64);
    }
    __shared__ float red[4][4];
    if (lane == 0) { red[wave][0] = b[0]; red[wave][1] = b[1]; red[wave][2] = b[2]; red[wave][3] = b[3]; }
    __syncthreads();
    if (c < 4)
        bsum[(o << 2) + c] = red[0][c] + red[1][c] + red[2][c] + red[3][c];
}

// Block tile: BM=128 x BN=128, BK=64, 4 waves (2x2), wave tile 64x64.
// A: async global_load_lds into linear f32 [64][128] (X is [k][m], m contig).
// B: direct global->VGPR bf16 fragments from L2-resident Bg. No B LDS.
__global__ __launch_bounds__(256, 5) void deconv_gemm(
    const float* __restrict__ X, const short* __restrict__ Bg,
    const float* __restrict__ Bsum, float* __restrict__ Y)
{
    __shared__ float As[64][128];   // 32 KB, linear (global_load_lds dest)

    const int tid = threadIdx.x;
    int bid = blockIdx.x;
    bid = ((bid & 7) << 10) | (bid >> 3);   // XCD-chunked swizzle (8192 = 8*1024)
    const int cb = bid & 7;         // col tile: 8 per row-tile, consecutive on one XCD
    const int rb = bid >> 3;        // row tile 0..1023
    const int p0 = rb << 7;
    const int n  = p0 >> 12;
    const int q0 = p0 & 4095;

    const int wave = __builtin_amdgcn_readfirstlane(tid >> 6);
    const int lane = tid & 63;
    const int wm = wave >> 1, wn = wave & 1;
    const int l15 = lane & 15, g = lane >> 4;

    f32x4 acc[4][4] = {};

    // A staging source: lane covers 16 B of row (c0 + krow); lane>>5 = row parity.
    const float* xbase = X + ((size_t)n << 20) + (size_t)q0 + ((lane & 31) << 2);
    const int rl = lane >> 5;

    // B fragment base: col = cb*128 + wn*64 + fn*16 + l15, k = c0 + ks*32 + g*8 + j
    const short* bgbase = Bg + ((size_t)((cb << 7) + (wn << 6) + l15) << 8) + (g << 3);

    for (int t = 0; t < 4; ++t) {
        const int c0 = t << 6;
        // stage A tile: wave handles local rows wave*16 .. wave*16+15 (2 rows/instr)
        #pragma unroll
        for (int i = 0; i < 8; ++i) {
            const int krow = (wave << 4) + (i << 1);
            __builtin_amdgcn_global_load_lds(
                (gvoid*)(xbase + ((size_t)(c0 + krow + rl) << 12)),
                (lvoid*)&As[krow][0], 16, 0, 0);
        }
        __syncthreads();   // drains vmcnt -> A tile visible

        #pragma unroll
        for (int ks = 0; ks < 2; ++ks) {
            short8 bfr[4];
            #pragma unroll
            for (int fn = 0; fn < 4; ++fn)
                bfr[fn] = *(const short8*)(bgbase + ((fn << 4) << 8) + c0 + (ks << 5));
            #pragma unroll
            for (int fm = 0; fm < 4; ++fm) {
                const int m = (wm << 6) + (fm << 4) + l15;
                short8 afr;
                #pragma unroll
                for (int j = 0; j < 8; ++j)
                    afr[j] = f2bf(As[(ks << 5) + (g << 3) + j][m]);
                #pragma unroll
                for (int fn = 0; fn < 4; ++fn)
                    acc[fm][fn] = __builtin_amdgcn_mfma_f32_16x16x32_bf16(afr, bfr[fn], acc[fm][fn], 0, 0, 0);
            }
        }
        __syncthreads();   // tile consumed before next overwrite
    }

    // Epilogue (mapping verified in rounds 1-2): pixel = wm*64 + fm*16 + 4g + r,
    // col = cb*128 + wn*64 + fn*16 + l15. lane^1 pair-swap merges kw=0/1 so each
    // lane stores one contiguous float4.
    const int ih = (q0 >> 6) + wm;
    #pragma unroll
    for (int fn = 0; fn < 4; ++fn) {
        const int col = (cb << 7) + (wn << 6) + (fn << 4) + l15;
        const float bv = Bsum[col];
        const int o = col >> 2;
        const int h = (ih << 1) + ((col >> 1) & 1);
        float* yrow = Y + ((((size_t)n << 8) + (size_t)o) << 14) + ((size_t)h << 7);
        #pragma unroll
        for (int fm = 0; fm < 4; ++fm) {
            const float v0 = acc[fm][fn][0] + bv;
            const float v1 = acc[fm][fn][1] + bv;
            const float v2 = acc[fm][fn][2] + bv;
            const float v3 = acc[fm][fn][3] + bv;
            const float p0v = __shfl_xor(v0, 1, 64);
            const float p1v = __shfl_xor(v1, 1, 64);
            const float p2v = __shfl_xor(v2, 1, 64);
            const float p3v = __shfl_xor(v3, 1, 64);
            const int iw0 = (fm << 4) + (g << 2);
            f32x4 st; int w;
            if (!(lane & 1)) { st = (f32x4){v0, p0v, v1, p1v}; w = (iw0 << 1); }
            else             { st = (f32x4){p2v, v2, p3v, v3}; w = (iw0 << 1) + 4; }
            *(f32x4*)(yrow + w) = st;
        }
    }
}

extern "C" void kernel_launch(void* const* d_in, const int* in_sizes, int n_in,
                              void* d_out, int out_size, void* d_ws, size_t ws_size,
                              hipStream_t stream) {
    const float* X = (const float*)d_in[0];   // batches (32,256,64,64)
    const float* W = (const float*)d_in[1];   // weights (256,256,2,2)
    const float* B = (const float*)d_in[2];   // biases  (256,256,2,2)
    short* Bg   = (short*)d_ws;                       // 512 KiB bf16 W in [col][k]
    float* bsum = (float*)((char*)d_ws + (1024 * 256 * sizeof(short)));  // 4 KiB
    prep_wb<<<256, 256, 0, stream>>>(W, B, Bg, bsum);
    deconv_gemm<<<8192, 256, 0, stream>>>(X, Bg, bsum, (float*)d_out);
}

// Round 4
// 282.107 us; speedup vs baseline: 2.9483x; 2.9483x over previous
//
#include <hip/hip_runtime.h>
#include <hip/hip_bf16.h>

typedef __attribute__((ext_vector_type(8))) short short8;
typedef __attribute__((ext_vector_type(4))) float f32x4;

// X: (32, 256, 64, 64) f32 ; W,B: (256, 256, 2, 2) f32 ; out: (32, 256, 128, 128) f32
// GEMM view: M = 131072 pixels, N = 1024 (col = o*4 + kh*2 + kw), K = 256.

__device__ __forceinline__ short f2bf(float f) {
    union { __hip_bfloat16 h; short s; } u; u.h = __float2bfloat16(f); return u.s;
}

// One-shot prep: W (256,256,2,2) f32 -> Bg[col][k] bf16 (1024 x 256), and
// bsum[col] = sum_c biases[o][c][kl].
__global__ __launch_bounds__(256) void prep_wb(
    const float* __restrict__ W, const float* __restrict__ B,
    short* __restrict__ Bg, float* __restrict__ bsum)
{
    const int o = blockIdx.x, c = threadIdx.x;
    const int wave = c >> 6, lane = c & 63;
    f32x4 w = *(const f32x4*)(W + ((size_t)o << 10) + (c << 2));
    #pragma unroll
    for (int kl = 0; kl < 4; ++kl)
        Bg[(size_t)(((o << 2) + kl) << 8) + c] = f2bf(w[kl]);

    f32x4 b = *(const f32x4*)(B + ((size_t)o << 10) + (c << 2));
    #pragma unroll
    for (int off = 32; off >= 1; off >>= 1) {
        b[0] += __shfl_down(b[0], off, 64);
        b[1] += __shfl_down(b[1], off, 64);
        b[2] += __shfl_down(b[2], off, 64);
        b[3] += __shfl_down(b[3], off, 64);
    }
    __shared__ float red[4][4];
    if (lane == 0) { red[wave][0] = b[0]; red[wave][1] = b[1]; red[wave][2] = b[2]; red[wave][3] = b[3]; }
    __syncthreads();
    if (c < 4)
        bsum[(o << 2) + c] = red[0][c] + red[1][c] + red[2][c] + red[3][c];
}

// Block tile: BM=128 x BN=128, BK=32, 8 waves (4m x 2n), wave tile 32x64.
// A,B staged bf16 [row][32k] (64 B rows), double-buffered, XOR-swizzled
// (slot ^= (row>>1)&3 -> 2-way bank access = free). T14: issue next-tile
// global loads before compute, LDS-write after, 1 barrier/tile.
__global__ __launch_bounds__(512, 4) void deconv_gemm(
    const float* __restrict__ X, const short* __restrict__ Bg,
    const float* __restrict__ Bsum, float* __restrict__ Y)
{
    __shared__ short As[2][128 * 32];   // 8 KB per buffer
    __shared__ short Bs[2][128 * 32];   // 8 KB per buffer

    const int tid = threadIdx.x;
    int bid = blockIdx.x;
    const int L  = ((bid & 7) << 10) | (bid >> 3);   // XCD-chunked, bijective (8192 = 8*1024)
    const int cb = L & 7;          // 8 col-tiles sharing an A tile are consecutive -> same XCD L2
    const int rb = L >> 3;
    const int p0 = rb << 7;
    const int n  = p0 >> 12;
    const int q0 = p0 & 4095;

    const int wave = tid >> 6, lane = tid & 63;
    const int wm = wave >> 1, wn = wave & 1;   // 4x2 wave grid, wave tile 32x64
    const int l15 = lane & 15, g = lane >> 4;

    f32x4 acc[2][4] = {};

    // ---- staging ownership ----
    // A: thread owns pixel am (0..127), k-quad akq (0..3): 8 scalar f32 loads
    //    (each wave-instr = 64 consecutive pixels = 256 B coalesced), cvt,
    //    one ds_write_b128.
    const int am  = tid & 127;
    const int akq = tid >> 7;
    const float* xp = X + ((size_t)n << 20) + (size_t)(q0 + am);
    const int aw_idx = am * 32 + (((akq << 3)) ^ ((((am >> 1) & 3)) << 3));
    // B: thread owns col bcol (0..127), k-slot bks: one b128 load from
    //    L2-resident bf16 Bg, one ds_write_b128.
    const int bcol = tid >> 2;
    const int bks  = tid & 3;
    const short* bgp = Bg + ((size_t)((cb << 7) + bcol) << 8) + (bks << 3);
    const int bw_idx = bcol * 32 + (((bks << 3)) ^ ((((bcol >> 1) & 3)) << 3));

    // ---- fragment read addresses (swizzled, 2-way = free) ----
    const int mloc = (wm << 5) + l15;           // + fm*16
    const int cloc = (wn << 6) + l15;           // + fn*16

    // prologue: stage tile 0
    float aL[8]; short8 bL;
    #pragma unroll
    for (int j = 0; j < 8; ++j)
        aL[j] = xp[(size_t)((akq << 3) + j) << 12];
    bL = *(const short8*)bgp;
    {
        short8 av;
        #pragma unroll
        for (int j = 0; j < 8; ++j) av[j] = f2bf(aL[j]);
        *(short8*)&As[0][aw_idx] = av;
        *(short8*)&Bs[0][bw_idx] = bL;
    }
    __syncthreads();

    for (int t = 0; t < 8; ++t) {
        const int cur = t & 1;
        // issue next tile's global loads (latency hides under compute below)
        if (t < 7) {
            const int c0 = (t + 1) << 5;
            #pragma unroll
            for (int j = 0; j < 8; ++j)
                aL[j] = xp[(size_t)(c0 + (akq << 3) + j) << 12];
            bL = *(const short8*)(bgp + c0);
        }

        // compute tile t
        short8 afr[2], bfr[4];
        #pragma unroll
        for (int fm = 0; fm < 2; ++fm) {
            const int m = mloc + (fm << 4);
            afr[fm] = *(const short8*)&As[cur][m * 32 + ((g << 3) ^ (((m >> 1) & 3) << 3))];
        }
        #pragma unroll
        for (int fn = 0; fn < 4; ++fn) {
            const int c = cloc + (fn << 4);
            bfr[fn] = *(const short8*)&Bs[cur][c * 32 + ((g << 3) ^ (((c >> 1) & 3) << 3))];
        }
        #pragma unroll
        for (int fm = 0; fm < 2; ++fm)
            #pragma unroll
            for (int fn = 0; fn < 4; ++fn)
                acc[fm][fn] = __builtin_amdgcn_mfma_f32_16x16x32_bf16(afr[fm], bfr[fn], acc[fm][fn], 0, 0, 0);

        // write next tile to the other buffer, then one barrier
        if (t < 7) {
            short8 av;
            #pragma unroll
            for (int j = 0; j < 8; ++j) av[j] = f2bf(aL[j]);
            *(short8*)&As[cur ^ 1][aw_idx] = av;
            *(short8*)&Bs[cur ^ 1][bw_idx] = bL;
            __syncthreads();
        }
    }

    // Epilogue (mapping verified rounds 1-3): pixel = wm*32 + fm*16 + 4g + r,
    // col = cb*128 + wn*64 + fn*16 + l15. lane^1 pair-swap merges kw=0/1 so
    // each lane stores one contiguous float4; 8 lanes cover 128 B per row.
    const int ihbase = q0 >> 6;
    float bvv[4]; int colv[4];
    #pragma unroll
    for (int fn = 0; fn < 4; ++fn) {
        colv[fn] = (cb << 7) + (wn << 6) + (fn << 4) + l15;
        bvv[fn] = Bsum[colv[fn]];
    }
    #pragma unroll
    for (int fm = 0; fm < 2; ++fm) {
        const int ph = (wm << 5) + (fm << 4);          // pixel base (multiple of 16)
        const int ih = ihbase + (ph >> 6);
        const int iwb = (((ph & 63) + (g << 2)) << 1); // output w base for this frag
        #pragma unroll
        for (int fn = 0; fn < 4; ++fn) {
            const int col = colv[fn];
            const int o = col >> 2;
            const int h = (ih << 1) + ((col >> 1) & 1);
            float* yrow = Y + ((((size_t)n << 8) + (size_t)o) << 14) + ((size_t)h << 7);
            const float v0 = acc[fm][fn][0] + bvv[fn];
            const float v1 = acc[fm][fn][1] + bvv[fn];
            const float v2 = acc[fm][fn][2] + bvv[fn];
            const float v3 = acc[fm][fn][3] + bvv[fn];
            const float p0v = __shfl_xor(v0, 1, 64);
            const float p1v = __shfl_xor(v1, 1, 64);
            const float p2v = __shfl_xor(v2, 1, 64);
            const float p3v = __shfl_xor(v3, 1, 64);
            f32x4 st; int w;
            if (!(lane & 1)) { st = (f32x4){v0, p0v, v1, p1v}; w = iwb; }
            else             { st = (f32x4){p2v, v2, p3v, v3}; w = iwb + 4; }
            *(f32x4*)(yrow + w) = st;
        }
    }
}

extern "C" void kernel_launch(void* const* d_in, const int* in_sizes, int n_in,
                              void* d_out, int out_size, void* d_ws, size_t ws_size,
                              hipStream_t stream) {
    const float* X = (const float*)d_in[0];   // batches (32,256,64,64)
    const float* W = (const float*)d_in[1];   // weights (256,256,2,2)
    const float* B = (const float*)d_in[2];   // biases  (256,256,2,2)
    short* Bg   = (short*)d_ws;                       // 512 KiB bf16 W in [col][k]
    float* bsum = (float*)((char*)d_ws + (1024 * 256 * sizeof(short)));  // 4 KiB
    prep_wb<<<256, 256, 0, stream>>>(W, B, Bg, bsum);
    deconv_gemm<<<8192, 512, 0, stream>>>(X, Bg, bsum, (float*)d_out);
}